// Round 9
// baseline (341.024 us; speedup 1.0000x reference)
//
#include <hip/hip_runtime.h>

#define N 8192
#define NNB 512                        // blocks that also do NN
#define SCB 1536                       // scan-only blocks
#define GRID_B (NNB + SCB)             // 2048 = co-resident at 8 blocks/CU
#define CQUADS 512                     // quads per chunk (8 KB)
#define NCHUNKS (N * (N / 4) / CQUADS) // 32768
#define NN_CH 13                       // chunks per NN block
#define SC_CH 17                       // chunks per scan-only block
#define SLOT_CAP 512                   // LDS hit slots per block (mean ~26)
#define GCHUNK 1024                    // gts per LDS chunk

static_assert(NNB * NN_CH + SCB * SC_CH == NCHUNKS, "chunk split must cover A");

// ws layout (bytes):
//   qpq  @ 0       float4[8192]   (128 KiB)
//   sync @ 131072  uint[3] = { done, finish, lsum(float bits) }

// ---------------------------------------------------------------------------
// Single fused kernel.
// Blocks [0, NNB): nearest-gt argmin + normal gather; publish qpq[j] =
//   (qx,qy,qz, preds_j.q_j) with agent-scope stores, fence, bump `done`.
//   Then stream NN_CH chunks of A.
// Blocks [NNB, GRID_B): stream SC_CH chunks of A.
// All blocks: collect nonzero-A entries in an LDS hit buffer, then (after
//   their ~44 us of streaming, when done==NNB is long since true) spin-check,
//   acquire, compute the loss over their own hits, atomicAdd into lsum;
//   the last block (finish counter) stores lsum to out.
// ---------------------------------------------------------------------------
__global__ __launch_bounds__(256) void fused_all(
        const float* __restrict__ preds,
        const float* __restrict__ gts,
        const float* __restrict__ gn,
        float* __restrict__ qpq,            // float4-shaped, accessed as floats
        const float4* __restrict__ A4,
        unsigned int* __restrict__ sync,    // {done, finish, lsum}
        float* __restrict__ out) {
    __shared__ __align__(16) float sgf[GCHUNK * 3];   // 12 KiB; reused as hbuf
    __shared__ unsigned int scnt;
    __shared__ float wsum[4];

    const int tid = threadIdx.x;
    const int b   = blockIdx.x;

    int ch0, nch;
    if (b < NNB) {
        // ---------------- NN part ------------------------------------------
        const int lane = tid & 63;
        const int wv   = tid >> 6;
        const int j0   = b * 16 + wv * 4;

        float px[4], py[4], pz[4], bestV[4];
        int bestI[4];
        #pragma unroll
        for (int k = 0; k < 4; ++k) {
            px[k] = preds[(j0 + k) * 3 + 0];
            py[k] = preds[(j0 + k) * 3 + 1];
            pz[k] = preds[(j0 + k) * 3 + 2];
            bestV[k] = 3.4e38f;
            bestI[k] = 0;
        }

        for (int c = 0; c < N / GCHUNK; ++c) {
            #pragma unroll
            for (int s = 0; s < GCHUNK * 3 / 256; ++s) {
                const int t = s * 256 + tid;
                sgf[t] = gts[c * GCHUNK * 3 + t];          // coalesced dwords
            }
            __syncthreads();

            #pragma unroll 4
            for (int it = 0; it < GCHUNK / 64; ++it) {
                const int t  = it * 64 + lane;
                const float gx = sgf[t * 3 + 0];           // 2-way alias: free
                const float gy = sgf[t * 3 + 1];
                const float gz = sgf[t * 3 + 2];
                float gg = gx * gx;
                gg = fmaf(gy, gy, gg);
                gg = fmaf(gz, gz, gg);
                const int gi = c * GCHUNK + t;
                #pragma unroll
                for (int k = 0; k < 4; ++k) {
                    float d = gx * px[k];
                    d = fmaf(gy, py[k], d);
                    d = fmaf(gz, pz[k], d);
                    const float v = fmaf(-2.0f, d, gg);
                    if (v < bestV[k]) { bestV[k] = v; bestI[k] = gi; }
                }
            }
            __syncthreads();
        }

        // lexicographic (val, idx) min across the 64-lane wave
        #pragma unroll
        for (int d = 1; d < 64; d <<= 1) {
            #pragma unroll
            for (int k = 0; k < 4; ++k) {
                const float ov = __shfl_xor(bestV[k], d);
                const int   oi = __shfl_xor(bestI[k], d);
                if (ov < bestV[k] || (ov == bestV[k] && oi < bestI[k])) {
                    bestV[k] = ov; bestI[k] = oi;
                }
            }
        }

        // publish qpq with agent-scope stores (cross-XCD visibility)
        if (lane == 0) {
            #pragma unroll
            for (int k = 0; k < 4; ++k) {
                const int bi = bestI[k];
                const float qx = gn[bi * 3 + 0];
                const float qy = gn[bi * 3 + 1];
                const float qz = gn[bi * 3 + 2];
                const float pq = px[k] * qx + py[k] * qy + pz[k] * qz;
                float* dst = qpq + (size_t)(j0 + k) * 4;
                __hip_atomic_store(dst + 0, qx, __ATOMIC_RELAXED, __HIP_MEMORY_SCOPE_AGENT);
                __hip_atomic_store(dst + 1, qy, __ATOMIC_RELAXED, __HIP_MEMORY_SCOPE_AGENT);
                __hip_atomic_store(dst + 2, qz, __ATOMIC_RELAXED, __HIP_MEMORY_SCOPE_AGENT);
                __hip_atomic_store(dst + 3, pq, __ATOMIC_RELAXED, __HIP_MEMORY_SCOPE_AGENT);
            }
            __threadfence();                  // release: stores before done++
        }
        __syncthreads();
        if (tid == 0) atomicAdd(&sync[0], 1u);

        ch0 = b * NN_CH;
        nch = NN_CH;
    } else {
        ch0 = NNB * NN_CH + (b - NNB) * SC_CH;
        nch = SC_CH;
    }

    // ---------------- A-scan: collect hits in LDS --------------------------
    if (tid == 0) scnt = 0u;
    __syncthreads();                       // sgf free for reuse; scnt visible

    uint2* hbuf = (uint2*)sgf;

    for (int cc = 0; cc < nch; ++cc) {
        const int base = (ch0 + cc) * CQUADS + tid;
        const float4 a0 = A4[base];
        const float4 a1 = A4[base + 256];

        #pragma unroll
        for (int h = 0; h < 2; ++h) {
            const float4 a = h ? a1 : a0;
            const int u = h ? (base + 256) : base;
            if (a.x != 0.0f || a.y != 0.0f || a.z != 0.0f || a.w != 0.0f) {
                const unsigned int i  = (unsigned)(u >> 11);
                const unsigned int j0 = (unsigned)((u & 2047) << 2);
                const float av[4] = { a.x, a.y, a.z, a.w };
                #pragma unroll
                for (int c = 0; c < 4; ++c) {
                    if (av[c] != 0.0f) {
                        const unsigned int p = atomicAdd(&scnt, 1u);
                        if (p < SLOT_CAP) {
                            hbuf[p] = make_uint2((i << 13) | (j0 + c),
                                                 __float_as_uint(av[c]));
                        }
                    }
                }
            }
        }
    }

    __syncthreads();

    // ---------------- wait for qpq (done==NNB long before we get here) -----
    if (tid == 0) {
        unsigned int d;
        do {
            d = __hip_atomic_load(&sync[0], __ATOMIC_RELAXED,
                                  __HIP_MEMORY_SCOPE_AGENT);
            if (d < NNB) __builtin_amdgcn_s_sleep(16);
        } while (d < NNB);
    }
    __syncthreads();
    __threadfence();                       // acquire before qpq reads

    // ---------------- loss over own hits -----------------------------------
    const unsigned int n = scnt < SLOT_CAP ? scnt : SLOT_CAP;
    float sum = 0.0f;
    for (unsigned int t = tid; t < n; t += 256) {
        const uint2 h = hbuf[t];
        const unsigned int i = h.x >> 13;
        const unsigned int j = h.x & 8191u;
        const float av = __uint_as_float(h.y);
        const float* qf = qpq + (size_t)j * 4;
        const float qx = __hip_atomic_load(qf + 0, __ATOMIC_RELAXED, __HIP_MEMORY_SCOPE_AGENT);
        const float qy = __hip_atomic_load(qf + 1, __ATOMIC_RELAXED, __HIP_MEMORY_SCOPE_AGENT);
        const float qz = __hip_atomic_load(qf + 2, __ATOMIC_RELAXED, __HIP_MEMORY_SCOPE_AGENT);
        const float qw = __hip_atomic_load(qf + 3, __ATOMIC_RELAXED, __HIP_MEMORY_SCOPE_AGENT);
        float d = preds[i * 3 + 0] * qx;
        d = fmaf(preds[i * 3 + 1], qy, d);
        d = fmaf(preds[i * 3 + 2], qz, d);
        d = (d - qw) * av;
        sum = fmaf(d, d, sum);
    }

    #pragma unroll
    for (int d = 32; d > 0; d >>= 1) sum += __shfl_down(sum, d);
    if ((tid & 63) == 0) wsum[tid >> 6] = sum;
    __syncthreads();

    if (tid == 0) {
        const float bsum = wsum[0] + wsum[1] + wsum[2] + wsum[3];
        atomicAdd((float*)&sync[2], bsum);
        __threadfence();                   // lsum add before finish++
        const unsigned int f = atomicAdd(&sync[1], 1u);
        if (f == GRID_B - 1) {             // last block: publish result
            __threadfence();
            out[0] = __hip_atomic_load((float*)&sync[2], __ATOMIC_RELAXED,
                                       __HIP_MEMORY_SCOPE_AGENT);
        }
    }
}

extern "C" void kernel_launch(void* const* d_in, const int* in_sizes, int n_in,
                              void* d_out, int out_size, void* d_ws, size_t ws_size,
                              hipStream_t stream) {
    const float* preds = (const float*)d_in[0];
    const float* gts   = (const float*)d_in[1];
    const float* gn    = (const float*)d_in[2];
    const float* A     = (const float*)d_in[3];
    float* out = (float*)d_out;

    char* ws = (char*)d_ws;
    float*        qpq  = (float*)(ws);
    unsigned int* sync = (unsigned int*)(ws + 131072);

    hipMemsetAsync(sync, 0, 12, stream);   // done=0, finish=0, lsum=0.0f
    fused_all<<<GRID_B, 256, 0, stream>>>(
        preds, gts, gn, qpq, (const float4*)A, sync, out);
}

// Round 10
// 89.634 us; speedup vs baseline: 3.8046x; 3.8046x over previous
//
#include <hip/hip_runtime.h>

#define N 8192
#define NNB 512                        // blocks that also do NN
#define SCB 1536                       // scan-only blocks
#define GRID_B (NNB + SCB)             // 2048 = co-resident at 8 blocks/CU
#define CQUADS 512                     // quads per chunk (8 KB)
#define NCHUNKS (N * (N / 4) / CQUADS) // 32768
#define NN_CH 13                       // chunks per NN block
#define SC_CH 17                       // chunks per scan-only block
#define SLOT_CAP 512                   // LDS hit slots per block (mean ~26)
#define GCHUNK 1024                    // gts per LDS chunk

static_assert(NNB * NN_CH + SCB * SC_CH == NCHUNKS, "chunk split must cover A");

// ws layout (bytes):
//   qpq     @ 0       float[8192*4]  (128 KiB)  - sc1-published NN results
//   done    @ 131072  uint           (memset to 0 each call)
//   partial @ 131328  float[2048]    (8 KiB)    - per-block loss partials

// ---------------------------------------------------------------------------
// Fused kernel.
// Blocks [0, NNB): nearest-gt argmin + normal gather; publish qpq[j] =
//   (qx,qy,qz, preds_j.q_j) via sc1 (agent-scope) stores; __syncthreads
//   drains vmcnt(0); then done++. Then stream NN_CH chunks of A.
// Blocks [NNB, GRID_B): stream SC_CH chunks of A.
// All blocks: collect nonzero-A entries in LDS; after streaming (~44 us,
//   done==NNB long since true) spin-check done, then compute the loss over
//   their own hits (sc1 qpq loads bypass the non-coherent L2s) and store
//   partial[b] with a plain store. NO fences, NO same-address atomic storms.
// ---------------------------------------------------------------------------
__global__ __launch_bounds__(256) void fused_all(
        const float* __restrict__ preds,
        const float* __restrict__ gts,
        const float* __restrict__ gn,
        float* __restrict__ qpq,            // float4-shaped, accessed as floats
        const float4* __restrict__ A4,
        unsigned int* __restrict__ done,
        float* __restrict__ partial) {
    __shared__ __align__(16) float sgf[GCHUNK * 3];   // 12 KiB; reused as hbuf
    __shared__ unsigned int scnt;
    __shared__ float wsum[4];

    const int tid = threadIdx.x;
    const int b   = blockIdx.x;

    int ch0, nch;
    if (b < NNB) {
        // ---------------- NN part ------------------------------------------
        const int lane = tid & 63;
        const int wv   = tid >> 6;
        const int j0   = b * 16 + wv * 4;

        float px[4], py[4], pz[4], bestV[4];
        int bestI[4];
        #pragma unroll
        for (int k = 0; k < 4; ++k) {
            px[k] = preds[(j0 + k) * 3 + 0];
            py[k] = preds[(j0 + k) * 3 + 1];
            pz[k] = preds[(j0 + k) * 3 + 2];
            bestV[k] = 3.4e38f;
            bestI[k] = 0;
        }

        for (int c = 0; c < N / GCHUNK; ++c) {
            #pragma unroll
            for (int s = 0; s < GCHUNK * 3 / 256; ++s) {
                const int t = s * 256 + tid;
                sgf[t] = gts[c * GCHUNK * 3 + t];          // coalesced dwords
            }
            __syncthreads();

            #pragma unroll 4
            for (int it = 0; it < GCHUNK / 64; ++it) {
                const int t  = it * 64 + lane;
                const float gx = sgf[t * 3 + 0];           // 2-way alias: free
                const float gy = sgf[t * 3 + 1];
                const float gz = sgf[t * 3 + 2];
                float gg = gx * gx;
                gg = fmaf(gy, gy, gg);
                gg = fmaf(gz, gz, gg);
                const int gi = c * GCHUNK + t;
                #pragma unroll
                for (int k = 0; k < 4; ++k) {
                    float d = gx * px[k];
                    d = fmaf(gy, py[k], d);
                    d = fmaf(gz, pz[k], d);
                    const float v = fmaf(-2.0f, d, gg);
                    if (v < bestV[k]) { bestV[k] = v; bestI[k] = gi; }
                }
            }
            __syncthreads();
        }

        // lexicographic (val, idx) min across the 64-lane wave
        #pragma unroll
        for (int d = 1; d < 64; d <<= 1) {
            #pragma unroll
            for (int k = 0; k < 4; ++k) {
                const float ov = __shfl_xor(bestV[k], d);
                const int   oi = __shfl_xor(bestI[k], d);
                if (ov < bestV[k] || (ov == bestV[k] && oi < bestI[k])) {
                    bestV[k] = ov; bestI[k] = oi;
                }
            }
        }

        // publish qpq with sc1 stores (write through past the XCD L2)
        if (lane == 0) {
            #pragma unroll
            for (int k = 0; k < 4; ++k) {
                const int bi = bestI[k];
                const float qx = gn[bi * 3 + 0];
                const float qy = gn[bi * 3 + 1];
                const float qz = gn[bi * 3 + 2];
                const float pq = px[k] * qx + py[k] * qy + pz[k] * qz;
                float* dst = qpq + (size_t)(j0 + k) * 4;
                __hip_atomic_store(dst + 0, qx, __ATOMIC_RELAXED, __HIP_MEMORY_SCOPE_AGENT);
                __hip_atomic_store(dst + 1, qy, __ATOMIC_RELAXED, __HIP_MEMORY_SCOPE_AGENT);
                __hip_atomic_store(dst + 2, qz, __ATOMIC_RELAXED, __HIP_MEMORY_SCOPE_AGENT);
                __hip_atomic_store(dst + 3, pq, __ATOMIC_RELAXED, __HIP_MEMORY_SCOPE_AGENT);
            }
        }
        __syncthreads();                  // drains vmcnt(0): stores complete
        if (tid == 0) atomicAdd(done, 1u);

        ch0 = b * NN_CH;
        nch = NN_CH;
    } else {
        ch0 = NNB * NN_CH + (b - NNB) * SC_CH;
        nch = SC_CH;
    }

    // ---------------- A-scan: collect hits in LDS --------------------------
    if (tid == 0) scnt = 0u;
    __syncthreads();                       // sgf free for reuse; scnt visible

    uint2* hbuf = (uint2*)sgf;

    for (int cc = 0; cc < nch; ++cc) {
        const int base = (ch0 + cc) * CQUADS + tid;
        const float4 a0 = A4[base];
        const float4 a1 = A4[base + 256];

        #pragma unroll
        for (int h = 0; h < 2; ++h) {
            const float4 a = h ? a1 : a0;
            const int u = h ? (base + 256) : base;
            if (a.x != 0.0f || a.y != 0.0f || a.z != 0.0f || a.w != 0.0f) {
                const unsigned int i  = (unsigned)(u >> 11);
                const unsigned int j0 = (unsigned)((u & 2047) << 2);
                const float av[4] = { a.x, a.y, a.z, a.w };
                #pragma unroll
                for (int c = 0; c < 4; ++c) {
                    if (av[c] != 0.0f) {
                        const unsigned int p = atomicAdd(&scnt, 1u);
                        if (p < SLOT_CAP) {
                            hbuf[p] = make_uint2((i << 13) | (j0 + c),
                                                 __float_as_uint(av[c]));
                        }
                    }
                }
            }
        }
    }

    __syncthreads();

    // ---------------- wait for qpq (done==NNB long before we get here) -----
    if (tid == 0) {
        unsigned int d;
        do {
            d = __hip_atomic_load(done, __ATOMIC_RELAXED,
                                  __HIP_MEMORY_SCOPE_AGENT);
            if (d < NNB) __builtin_amdgcn_s_sleep(16);
        } while (d < NNB);
    }
    __syncthreads();

    // ---------------- loss over own hits (sc1 qpq loads, no fence) ---------
    const unsigned int n = scnt < SLOT_CAP ? scnt : SLOT_CAP;
    float sum = 0.0f;
    for (unsigned int t = tid; t < n; t += 256) {
        const uint2 h = hbuf[t];
        const unsigned int i = h.x >> 13;
        const unsigned int j = h.x & 8191u;
        const float av = __uint_as_float(h.y);
        const float* qf = qpq + (size_t)j * 4;
        const float qx = __hip_atomic_load(qf + 0, __ATOMIC_RELAXED, __HIP_MEMORY_SCOPE_AGENT);
        const float qy = __hip_atomic_load(qf + 1, __ATOMIC_RELAXED, __HIP_MEMORY_SCOPE_AGENT);
        const float qz = __hip_atomic_load(qf + 2, __ATOMIC_RELAXED, __HIP_MEMORY_SCOPE_AGENT);
        const float qw = __hip_atomic_load(qf + 3, __ATOMIC_RELAXED, __HIP_MEMORY_SCOPE_AGENT);
        float d = preds[i * 3 + 0] * qx;
        d = fmaf(preds[i * 3 + 1], qy, d);
        d = fmaf(preds[i * 3 + 2], qz, d);
        d = (d - qw) * av;
        sum = fmaf(d, d, sum);
    }

    #pragma unroll
    for (int d = 32; d > 0; d >>= 1) sum += __shfl_down(sum, d);
    if ((tid & 63) == 0) wsum[tid >> 6] = sum;
    __syncthreads();
    if (tid == 0) {
        partial[b] = wsum[0] + wsum[1] + wsum[2] + wsum[3];  // plain store
    }
}

// ---------------------------------------------------------------------------
// Sum kernel: one block reduces the 2048 per-block partials into out[0].
// Kernel boundary provides cross-XCD coherence for partial[].
// ---------------------------------------------------------------------------
__global__ __launch_bounds__(256) void sum_kernel(
        const float* __restrict__ partial,
        float* __restrict__ out) {
    const int tid = threadIdx.x;
    float sum = 0.0f;
    #pragma unroll
    for (int s = 0; s < GRID_B / 256; ++s) sum += partial[s * 256 + tid];

    #pragma unroll
    for (int d = 32; d > 0; d >>= 1) sum += __shfl_down(sum, d);

    __shared__ float wsum[4];
    if ((tid & 63) == 0) wsum[tid >> 6] = sum;
    __syncthreads();
    if (tid == 0) out[0] = wsum[0] + wsum[1] + wsum[2] + wsum[3];
}

extern "C" void kernel_launch(void* const* d_in, const int* in_sizes, int n_in,
                              void* d_out, int out_size, void* d_ws, size_t ws_size,
                              hipStream_t stream) {
    const float* preds = (const float*)d_in[0];
    const float* gts   = (const float*)d_in[1];
    const float* gn    = (const float*)d_in[2];
    const float* A     = (const float*)d_in[3];
    float* out = (float*)d_out;

    char* ws = (char*)d_ws;
    float*        qpq     = (float*)(ws);
    unsigned int* done    = (unsigned int*)(ws + 131072);
    float*        partial = (float*)(ws + 131328);

    hipMemsetAsync(done, 0, 4, stream);
    fused_all<<<GRID_B, 256, 0, stream>>>(
        preds, gts, gn, qpq, (const float4*)A, done, partial);
    sum_kernel<<<1, 256, 0, stream>>>(partial, out);
}

// Round 11
// 54.333 us; speedup vs baseline: 6.2766x; 1.6497x over previous
//
#include <hip/hip_runtime.h>

#define N 8192
#define GRID_B 2048                     // uniform blocks, 8/CU co-resident
#define CQUADS 512                      // A quads per chunk (8 KB)
#define CPB 16                          // A chunks per block
#define GCH 1024                        // gts per NN chunk
#define NGCH (N / GCH)                  // 8 NN chunks (interleaved in iters 0..7)
#define PPB 4                           // preds per block (2048*4 = 8192)
#define SLOT_CAP 256                    // hit slots per block (mean ~24)

// ws layout (bytes):
//   qpq  @ 0       float4[8192]            (128 KiB)
//   cnt  @ 131072  uint[2048]              (8 KiB)
//   hits @ 139264  uint2[2048 * SLOT_CAP]  (4 MiB)

// ---------------------------------------------------------------------------
// Fused kernel, 2048 identical blocks. Block b owns preds [4b, 4b+4) and A
// chunks [16b, 16b+16). Per iteration: issue A-chunk loads; iters 0..7 also
// stage one gt-chunk into LDS and crunch the NN argmin for this block's 4
// preds (~128 VALU cycles — hidden under the A-load latency / other blocks'
// streaming); then detect nonzero A entries into an LDS hit buffer.
// Ends: cross-wave argmin -> qpq[4b..4b+3]; flush hits to private slot.
// No cross-block sync; NN cost is uniform (~2% duty) -> no BW dip, no tail.
// ---------------------------------------------------------------------------
__global__ __launch_bounds__(256, 8) void fused_kernel(
        const float* __restrict__ preds,
        const float* __restrict__ gts,
        const float* __restrict__ gn,
        float4* __restrict__ qpq,
        const float4* __restrict__ A4,
        unsigned int* __restrict__ cnt,
        uint2* __restrict__ hits,
        float* __restrict__ out) {
    __shared__ __align__(16) float sgf[GCH * 3];   // 12 KiB gt staging
    __shared__ uint2 hbuf[SLOT_CAP];               // 2 KiB hit buffer
    __shared__ unsigned int scnt;
    __shared__ float swV[4][PPB];
    __shared__ int   swI[4][PPB];

    const int tid  = threadIdx.x;
    const int b    = blockIdx.x;
    const int lane = tid & 63;
    const int wv   = tid >> 6;
    const int j0   = b * PPB;

    if (b == 0 && tid == 0) out[0] = 0.0f;         // read only by loss kernel

    float px[PPB], py[PPB], pz[PPB], bestV[PPB];
    int bestI[PPB];
    #pragma unroll
    for (int k = 0; k < PPB; ++k) {
        px[k] = preds[(j0 + k) * 3 + 0];           // wave-uniform -> scalarized
        py[k] = preds[(j0 + k) * 3 + 1];
        pz[k] = preds[(j0 + k) * 3 + 2];
        bestV[k] = 3.4e38f;
        bestI[k] = 0;
    }
    if (tid == 0) scnt = 0u;                       // visible at iter-0 sync

    for (int c = 0; c < CPB; ++c) {
        // ---- issue this iteration's A-chunk loads ------------------------
        const int base = (b * CPB + c) * CQUADS + tid;
        const float4 a0 = A4[base];
        const float4 a1 = A4[base + 256];

        // ---- iters 0..7: stage + crunch one gt chunk ---------------------
        if (c < NGCH) {
            const float4* g4 = (const float4*)gts + (size_t)c * (GCH * 3 / 4);
            const float4 t0 = g4[tid];
            const float4 t1 = g4[tid + 256];
            const float4 t2 = g4[tid + 512];
            float4* s4 = (float4*)sgf;
            s4[tid]       = t0;
            s4[tid + 256] = t1;
            s4[tid + 512] = t2;
            __syncthreads();

            // wave wv crunches local gts [wv*256, wv*256+256), 4 per lane
            #pragma unroll
            for (int m = 0; m < 4; ++m) {
                const int t  = wv * 256 + m * 64 + lane;
                const float gx = sgf[t * 3 + 0];   // stride-3: 2-way alias, free
                const float gy = sgf[t * 3 + 1];
                const float gz = sgf[t * 3 + 2];
                float gg = gx * gx;
                gg = fmaf(gy, gy, gg);
                gg = fmaf(gz, gz, gg);
                const int gi = c * GCH + t;
                #pragma unroll
                for (int k = 0; k < PPB; ++k) {
                    float d = gx * px[k];
                    d = fmaf(gy, py[k], d);
                    d = fmaf(gz, pz[k], d);
                    const float v = fmaf(-2.0f, d, gg);
                    if (v < bestV[k]) { bestV[k] = v; bestI[k] = gi; }
                }
            }
        }

        // ---- detect nonzero A entries ------------------------------------
        #pragma unroll
        for (int h = 0; h < 2; ++h) {
            const float4 a = h ? a1 : a0;
            const int u = h ? (base + 256) : base;
            if (a.x != 0.0f || a.y != 0.0f || a.z != 0.0f || a.w != 0.0f) {
                const unsigned int i  = (unsigned)(u >> 11);
                const unsigned int jq = (unsigned)((u & 2047) << 2);
                const float av[4] = { a.x, a.y, a.z, a.w };
                #pragma unroll
                for (int e = 0; e < 4; ++e) {
                    if (av[e] != 0.0f) {
                        const unsigned int p = atomicAdd(&scnt, 1u);
                        if (p < SLOT_CAP) {
                            hbuf[p] = make_uint2((i << 13) | (jq + e),
                                                 __float_as_uint(av[e]));
                        }
                    }
                }
            }
        }

        // protect sgf for next iteration's stage-write
        if (c < NGCH) __syncthreads();
    }

    // ---- cross-wave argmin + qpq publish ---------------------------------
    #pragma unroll
    for (int d = 1; d < 64; d <<= 1) {
        #pragma unroll
        for (int k = 0; k < PPB; ++k) {
            const float ov = __shfl_xor(bestV[k], d);
            const int   oi = __shfl_xor(bestI[k], d);
            if (ov < bestV[k] || (ov == bestV[k] && oi < bestI[k])) {
                bestV[k] = ov; bestI[k] = oi;
            }
        }
    }
    if (lane == 0) {
        #pragma unroll
        for (int k = 0; k < PPB; ++k) { swV[wv][k] = bestV[k]; swI[wv][k] = bestI[k]; }
    }
    __syncthreads();                   // swV/swI + scnt/hbuf all final

    if (tid < PPB) {                   // thread k finishes pred j0+k
        float bv = swV[0][tid];
        int   bi = swI[0][tid];
        #pragma unroll
        for (int w = 1; w < 4; ++w) {
            const float v = swV[w][tid];
            const int   i = swI[w][tid];
            if (v < bv || (v == bv && i < bi)) { bv = v; bi = i; }
        }
        const float qx = gn[bi * 3 + 0];
        const float qy = gn[bi * 3 + 1];
        const float qz = gn[bi * 3 + 2];
        const float ppx = preds[(j0 + tid) * 3 + 0];   // reload: avoid runtime
        const float ppy = preds[(j0 + tid) * 3 + 1];   // reg-array indexing
        const float ppz = preds[(j0 + tid) * 3 + 2];
        const float pq = ppx * qx + ppy * qy + ppz * qz;
        qpq[j0 + tid] = make_float4(qx, qy, qz, pq);
    }

    // ---- flush hits to private slot --------------------------------------
    const unsigned int n = scnt < SLOT_CAP ? scnt : SLOT_CAP;
    uint2* slot = hits + (size_t)b * SLOT_CAP;
    for (unsigned int t = tid; t < n; t += 256) slot[t] = hbuf[t];
    if (tid == 0) cnt[b] = n;
}

// ---------------------------------------------------------------------------
// Loss kernel: 128 blocks x 4 waves; each wave handles 4 slots, one
// lane-parallel pass per slot (cnt ~24 < 64). 128 total atomics into out.
// ---------------------------------------------------------------------------
__global__ __launch_bounds__(256) void loss_kernel(
        const float* __restrict__ preds,
        const float4* __restrict__ qpq,
        const unsigned int* __restrict__ cnt,
        const uint2* __restrict__ hits,
        float* __restrict__ out) {
    const int lane    = threadIdx.x & 63;
    const int wave_id = blockIdx.x * 4 + (threadIdx.x >> 6);  // 0..511
    float sum = 0.0f;

    #pragma unroll
    for (int s = 0; s < 4; ++s) {
        const int sb = wave_id * 4 + s;                       // 0..2047
        const unsigned int c = cnt[sb] < SLOT_CAP ? cnt[sb] : SLOT_CAP;
        const uint2* slot = hits + (size_t)sb * SLOT_CAP;
        for (unsigned int t = lane; t < c; t += 64) {
            const uint2 h = slot[t];
            const unsigned int i = h.x >> 13;
            const unsigned int j = h.x & 8191u;
            const float av = __uint_as_float(h.y);
            const float4 q = qpq[j];
            float d = preds[i * 3 + 0] * q.x;
            d = fmaf(preds[i * 3 + 1], q.y, d);
            d = fmaf(preds[i * 3 + 2], q.z, d);
            d = (d - q.w) * av;
            sum = fmaf(d, d, sum);
        }
    }

    #pragma unroll
    for (int d = 32; d > 0; d >>= 1) sum += __shfl_down(sum, d);

    __shared__ float wsum[4];
    if (lane == 0) wsum[threadIdx.x >> 6] = sum;
    __syncthreads();
    if (threadIdx.x == 0) {
        atomicAdd(out, wsum[0] + wsum[1] + wsum[2] + wsum[3]);
    }
}

extern "C" void kernel_launch(void* const* d_in, const int* in_sizes, int n_in,
                              void* d_out, int out_size, void* d_ws, size_t ws_size,
                              hipStream_t stream) {
    const float* preds = (const float*)d_in[0];
    const float* gts   = (const float*)d_in[1];
    const float* gn    = (const float*)d_in[2];
    const float* A     = (const float*)d_in[3];
    float* out = (float*)d_out;

    char* ws = (char*)d_ws;
    float4*       qpq  = (float4*)(ws);
    unsigned int* cnt  = (unsigned int*)(ws + 131072);
    uint2*        hits = (uint2*)(ws + 139264);

    fused_kernel<<<GRID_B, 256, 0, stream>>>(
        preds, gts, gn, qpq, (const float4*)A, cnt, hits, out);
    loss_kernel<<<128, 256, 0, stream>>>(preds, qpq, cnt, hits, out);
}

// Round 12
// 50.177 us; speedup vs baseline: 6.7965x; 1.0828x over previous
//
#include <hip/hip_runtime.h>

#define N 8192
#define NNB 512                        // blocks that also do NN
#define SCB 1536                       // scan-only blocks
#define GRID_B (NNB + SCB)             // 2048 = exactly co-resident
#define CQUADS 512                     // quads per chunk (8 KB)
#define NCHUNKS (N * (N / 4) / CQUADS) // 32768
#define NN_CH 13                       // chunks per NN block
#define SC_CH 17                       // chunks per scan-only block
#define SLOT_CAP 256                   // hit slots per block (mean ~24, 46 sigma)
#define GCHUNK 1024                    // gts per LDS chunk

static_assert(NNB * NN_CH + SCB * SC_CH == NCHUNKS, "chunk split must cover A");

// ws layout (bytes):
//   qpq  @ 0       float4[8192]            (128 KiB)
//   cnt  @ 131072  uint[2048]              (8 KiB)
//   hits @ 139264  uint2[2048 * SLOT_CAP]  (4 MiB)

// ---------------------------------------------------------------------------
// Fused kernel, one generation of 2048 blocks.
// Blocks [0, NNB): nearest-gt argmin + normal gather (qpq[j] =
//   (qx,qy,qz, preds_j.q_j)), then stream NN_CH chunks of A.
// Blocks [NNB, GRID_B): stream SC_CH chunks of A.
// Chunk shares are tuned so NN (~7 us ~= 4 chunk-times) equalizes finish
// times -> no slot-steal, no generation tail. Hits collected in LDS (the NN
// staging buffer, reused after a barrier), flushed once per block.
// ---------------------------------------------------------------------------
__global__ __launch_bounds__(256) void fused_kernel(
        const float* __restrict__ preds,
        const float* __restrict__ gts,
        const float* __restrict__ gn,
        float4* __restrict__ qpq,
        const float4* __restrict__ A4,
        unsigned int* __restrict__ cnt,
        uint2* __restrict__ hits,
        float* __restrict__ out) {
    __shared__ __align__(16) float sgf[GCHUNK * 3];   // 12 KiB; reused as hbuf
    __shared__ unsigned int scnt;

    const int tid = threadIdx.x;
    const int b   = blockIdx.x;

    int ch0, nch;
    if (b < NNB) {
        // ---------------- NN part ------------------------------------------
        if (b == 0 && tid == 0) out[0] = 0.0f;   // read only by loss kernel

        const int lane = tid & 63;
        const int wv   = tid >> 6;
        const int j0   = b * 16 + wv * 4;

        float px[4], py[4], pz[4], bestV[4];
        int bestI[4];
        #pragma unroll
        for (int k = 0; k < 4; ++k) {
            px[k] = preds[(j0 + k) * 3 + 0];
            py[k] = preds[(j0 + k) * 3 + 1];
            pz[k] = preds[(j0 + k) * 3 + 2];
            bestV[k] = 3.4e38f;
            bestI[k] = 0;
        }

        for (int c = 0; c < N / GCHUNK; ++c) {
            #pragma unroll
            for (int s = 0; s < GCHUNK * 3 / 256; ++s) {
                const int t = s * 256 + tid;
                sgf[t] = gts[c * GCHUNK * 3 + t];          // coalesced dwords
            }
            __syncthreads();

            #pragma unroll 4
            for (int it = 0; it < GCHUNK / 64; ++it) {
                const int t  = it * 64 + lane;
                const float gx = sgf[t * 3 + 0];           // 2-way alias: free
                const float gy = sgf[t * 3 + 1];
                const float gz = sgf[t * 3 + 2];
                float gg = gx * gx;
                gg = fmaf(gy, gy, gg);
                gg = fmaf(gz, gz, gg);
                const int gi = c * GCHUNK + t;
                #pragma unroll
                for (int k = 0; k < 4; ++k) {
                    float d = gx * px[k];
                    d = fmaf(gy, py[k], d);
                    d = fmaf(gz, pz[k], d);
                    const float v = fmaf(-2.0f, d, gg);
                    if (v < bestV[k]) { bestV[k] = v; bestI[k] = gi; }
                }
            }
            __syncthreads();
        }

        // lexicographic (val, idx) min across the 64-lane wave
        #pragma unroll
        for (int d = 1; d < 64; d <<= 1) {
            #pragma unroll
            for (int k = 0; k < 4; ++k) {
                const float ov = __shfl_xor(bestV[k], d);
                const int   oi = __shfl_xor(bestI[k], d);
                if (ov < bestV[k] || (ov == bestV[k] && oi < bestI[k])) {
                    bestV[k] = ov; bestI[k] = oi;
                }
            }
        }

        if (lane == 0) {
            #pragma unroll
            for (int k = 0; k < 4; ++k) {
                const int bi = bestI[k];
                const float qx = gn[bi * 3 + 0];
                const float qy = gn[bi * 3 + 1];
                const float qz = gn[bi * 3 + 2];
                const float pq = px[k] * qx + py[k] * qy + pz[k] * qz;
                qpq[j0 + k] = make_float4(qx, qy, qz, pq);
            }
        }

        ch0 = b * NN_CH;
        nch = NN_CH;
    } else {
        ch0 = NNB * NN_CH + (b - NNB) * SC_CH;
        nch = SC_CH;
    }

    // ---------------- A-scan part ------------------------------------------
    if (tid == 0) scnt = 0u;
    __syncthreads();                       // sgf free for reuse; scnt visible

    uint2* hbuf = (uint2*)sgf;
    uint2* slot = hits + (size_t)b * SLOT_CAP;

    for (int cc = 0; cc < nch; ++cc) {
        const int base = (ch0 + cc) * CQUADS + tid;
        const float4 a0 = A4[base];
        const float4 a1 = A4[base + 256];

        #pragma unroll
        for (int h = 0; h < 2; ++h) {
            const float4 a = h ? a1 : a0;
            const int u = h ? (base + 256) : base;
            if (a.x != 0.0f || a.y != 0.0f || a.z != 0.0f || a.w != 0.0f) {
                const unsigned int i  = (unsigned)(u >> 11);
                const unsigned int j0 = (unsigned)((u & 2047) << 2);
                const float av[4] = { a.x, a.y, a.z, a.w };
                #pragma unroll
                for (int c = 0; c < 4; ++c) {
                    if (av[c] != 0.0f) {
                        const unsigned int p = atomicAdd(&scnt, 1u);
                        if (p < SLOT_CAP) {
                            hbuf[p] = make_uint2((i << 13) | (j0 + c),
                                                 __float_as_uint(av[c]));
                        }
                    }
                }
            }
        }
    }

    __syncthreads();
    const unsigned int n = scnt < SLOT_CAP ? scnt : SLOT_CAP;
    for (unsigned int t = tid; t < n; t += 256) slot[t] = hbuf[t];
    if (tid == 0) cnt[b] = n;
}

// ---------------------------------------------------------------------------
// Loss kernel: 128 blocks x 4 waves; each wave handles 4 slots, one
// lane-parallel pass per slot (cnt ~24 < 64). 128 total atomics into out.
// ---------------------------------------------------------------------------
__global__ __launch_bounds__(256) void loss_kernel(
        const float* __restrict__ preds,
        const float4* __restrict__ qpq,
        const unsigned int* __restrict__ cnt,
        const uint2* __restrict__ hits,
        float* __restrict__ out) {
    const int lane    = threadIdx.x & 63;
    const int wave_id = blockIdx.x * 4 + (threadIdx.x >> 6);  // 0..511
    float sum = 0.0f;

    #pragma unroll
    for (int s = 0; s < 4; ++s) {
        const int sb = wave_id * 4 + s;                       // 0..2047
        const unsigned int c = cnt[sb] < SLOT_CAP ? cnt[sb] : SLOT_CAP;
        const uint2* slot = hits + (size_t)sb * SLOT_CAP;
        for (unsigned int t = lane; t < c; t += 64) {
            const uint2 h = slot[t];
            const unsigned int i = h.x >> 13;
            const unsigned int j = h.x & 8191u;
            const float av = __uint_as_float(h.y);
            const float4 q = qpq[j];
            float d = preds[i * 3 + 0] * q.x;
            d = fmaf(preds[i * 3 + 1], q.y, d);
            d = fmaf(preds[i * 3 + 2], q.z, d);
            d = (d - q.w) * av;
            sum = fmaf(d, d, sum);
        }
    }

    #pragma unroll
    for (int d = 32; d > 0; d >>= 1) sum += __shfl_down(sum, d);

    __shared__ float wsum[4];
    if (lane == 0) wsum[threadIdx.x >> 6] = sum;
    __syncthreads();
    if (threadIdx.x == 0) {
        atomicAdd(out, wsum[0] + wsum[1] + wsum[2] + wsum[3]);
    }
}

extern "C" void kernel_launch(void* const* d_in, const int* in_sizes, int n_in,
                              void* d_out, int out_size, void* d_ws, size_t ws_size,
                              hipStream_t stream) {
    const float* preds = (const float*)d_in[0];
    const float* gts   = (const float*)d_in[1];
    const float* gn    = (const float*)d_in[2];
    const float* A     = (const float*)d_in[3];
    float* out = (float*)d_out;

    char* ws = (char*)d_ws;
    float4*       qpq  = (float4*)(ws);
    unsigned int* cnt  = (unsigned int*)(ws + 131072);
    uint2*        hits = (uint2*)(ws + 139264);

    fused_kernel<<<GRID_B, 256, 0, stream>>>(
        preds, gts, gn, qpq, (const float4*)A, cnt, hits, out);
    loss_kernel<<<128, 256, 0, stream>>>(preds, qpq, cnt, hits, out);
}